// Round 6
// baseline (303.496 us; speedup 1.0000x reference)
//
#include <hip/hip_runtime.h>
#include <math.h>

#define BATCH 2048
#define TLEN  1440
#define T7    (TLEN * 7)      // 10080 dwords per batch row
#define CL0   48              // chunk 0 length (covers ENC_LEN=48 gt region)
#define CL2   16              // length of chunks 1..87
#define NCH   88              // total chunks per batch (1 + 87)
#define TREST (TLEN - CL0)    // 1392

// ---- workspace layout (float offsets) ----
#define PACK2_OFF 0                                  // float2[TLEN][BATCH] (ta,so)
#define PACKU_OFF (PACK2_OFF + 2 * TLEN * BATCH)     // float[TLEN][BATCH]  u
#define PACKG_OFF (PACKU_OFF + TLEN * BATCH)         // float[48][BATCH]    gt
#define INIT_OFF  (PACKG_OFF + 48 * BATCH)           // float2[BATCH] (Tz0, Tmid0)
#define E_OFF     (INIT_OFF + 2 * BATCH)             // [NCH][BATCH][8] chunk end-states
#define XC_OFF    (E_OFF + NCH * BATCH * 8)          // [NCH][BATCH][8] combined entry states
#define WS_FLOATS (XC_OFF + NCH * BATCH * 8)

__device__ __forceinline__ float sp_precise(float x) { return log1pf(expf(x)); }

struct Prm {
  float P[5], M[5], Q[5], K[5];
  float AZ, dtczw, dtcz, cInt, cHv, cDir;
};
// Derived params from raw inputs — recomputed per kernel (identical op order
// everywhere => bitwise-identical results; ~30 scalar ops, cheaper than a
// serial k0 prelude + ws round-trip).
__device__ __forceinline__ Prm make_prm(const float* rcR, const float* rcC,
                                        const float* winR, const float* hvg,
                                        const float* ing, const float* dg,
                                        const float* aw, const float* ar,
                                        const float* zc) {
  Prm p;
  float r[5], cc[5], rsum = 0.f;
  #pragma unroll
  for (int j = 0; j < 5; ++j) {
    r[j] = sp_precise(rcR[j]) * 0.1f;
    cc[j] = sp_precise(rcC[j]) * 1e-5f;
    rsum += r[j];
  }
  float w  = (sp_precise(winR[0]) + sp_precise(winR[1])) * 0.5f;
  float cz = sp_precise(zc[0]) * 1e-5f;
  float aW = sp_precise(aw[0]) * 0.5f, aR = sp_precise(ar[0]) * 0.5f;
  float dtcz = 900.f * cz;
  #pragma unroll
  for (int j = 0; j < 5; ++j) {
    p.P[j] = 900.f * r[j] * cc[j];
    p.M[j] = 1.f - 2.f * p.P[j];
    p.Q[j] = 900.f * cc[j] * ((j < 4) ? aW : aR);
    p.K[j] = dtcz * r[j];
  }
  p.AZ = 1.f - dtcz * (w + rsum);
  p.dtczw = dtcz * w;
  p.dtcz = dtcz;
  p.cInt = sp_precise(ing[0]) * 0.1f;
  p.cHv  = sp_precise(hvg[0]) * 0.1f;
  p.cDir = sp_precise(dg[0])  * 0.5f;
  return p;
}

// ============ K1: streaming MLP + forcing pack (weights via LDS) ============
// Block = 256 consecutive batches x 4 steps. Grid = 360 t-groups x 8 b-groups.
__global__ __launch_bounds__(256) void k1_pack(const float* __restrict__ X,
    const float* __restrict__ rcR, const float* __restrict__ rcC,
    const float* __restrict__ winR, const float* __restrict__ hvg,
    const float* __restrict__ W1, const float* __restrict__ B1,
    const float* __restrict__ W2, const float* __restrict__ B2,
    const float* __restrict__ ing, const float* __restrict__ dg,
    const float* __restrict__ aw, const float* __restrict__ ar,
    const float* __restrict__ zc, float* __restrict__ ws) {
  __shared__ float lds[256 * 29];   // 4 steps x 7 floats per row, stride 29
  __shared__ float ldsW[128];       // 32 x (w1a, w1b, b1, w2)
  int tg  = blockIdx.x >> 3;                   // 0..359
  int b0  = (blockIdx.x & 7) << 8;
  int t0r = tg * 4;
  int tid = threadIdx.x;
  int b   = b0 + tid;
  Prm p = make_prm(rcR, rcC, winR, hvg, ing, dg, aw, ar, zc);
  float b2 = B2[0];
  if (tid < 32) {
    ldsW[tid * 4 + 0] = W1[2 * tid];
    ldsW[tid * 4 + 1] = W1[2 * tid + 1];
    ldsW[tid * 4 + 2] = B1[tid];
    ldsW[tid * 4 + 3] = W2[tid];
  }
  // ---- stage 256 rows x 4 steps (7 aligned float4 per row) ----
  const float* base = X + ((size_t)b0 * TLEN + t0r) * 7;
  #pragma unroll
  for (int i = 0; i < 7; ++i) {
    int F = i * 256 + tid;                     // 0..1791
    int row = F / 7, q = F - row * 7;
    float4 v = *(const float4*)(base + (size_t)row * T7 + q * 4);
    int la = row * 29 + q * 4;
    lds[la] = v.x; lds[la + 1] = v.y; lds[la + 2] = v.z; lds[la + 3] = v.w;
  }
  // boundary gt for s==3 (needed only while t+1 <= 47)
  float gtb = 0.f;
  if (t0r < 44) gtb = X[(size_t)b * T7 + (size_t)(t0r + 4) * 7];
  __syncthreads();
  int j29 = tid * 29;
  float ta[4], so[4], x3[4], x4[4], x5[4], hv[4];
  #pragma unroll
  for (int s = 0; s < 4; ++s) {
    const float* x = &lds[j29 + s * 7];
    ta[s] = x[1]; so[s] = x[2]; x3[s] = x[3]; x4[s] = x[4]; x5[s] = x[5]; hv[s] = x[6];
  }
  // MLP: h-outer, one ds_read_b128 broadcast per h, reused across 4 steps
  float acc[4] = {b2, b2, b2, b2};
  #pragma unroll
  for (int h = 0; h < 32; ++h) {
    float4 wv = *(const float4*)&ldsW[h * 4];
    #pragma unroll
    for (int s = 0; s < 4; ++s) {
      float z = fmaf(wv.x, x3[s], fmaf(wv.y, x4[s], wv.z));
      acc[s] = fmaf(wv.w, fmaxf(z, 0.f), acc[s]);
    }
  }
  float2* pk2 = (float2*)(ws + PACK2_OFF);
  float*  pu  = ws + PACKU_OFF;
  float*  pg  = ws + PACKG_OFF;
  #pragma unroll
  for (int s = 0; s < 4; ++s) {
    float sch = __frcp_rn(1.f + __expf(-acc[s])) + x5[s];
    float q = fmaf(p.cInt, sch, fmaf(p.cHv, hv[s], p.cDir * so[s]));
    float u = fmaf(p.dtczw, ta[s], p.dtcz * q);
    int t = t0r + s;
    size_t o = (size_t)t * BATCH + b;
    pk2[o] = make_float2(ta[s], so[s]);        // coalesced 8B/lane
    pu[o]  = u;                                // coalesced 4B/lane
    if (t < 48) {
      float gt = (t < 47) ? ((s < 3) ? lds[j29 + (s + 1) * 7] : gtb) : 0.f;
      pg[o] = gt;
    }
  }
  if (tg == 0) {  // init states (Tz0, Tmid0), coalesced
    float tz0 = lds[j29], ta0 = lds[j29 + 1];
    ((float2*)(ws + INIT_OFF))[b] = make_float2(tz0, fmaf(0.7f, tz0, 0.3f * ta0));
  }
}

// ============ K2: chunk scan, full load prefetch per 16-step group ============
__global__ __launch_bounds__(256) void k2_scan(
    const float* __restrict__ rcR, const float* __restrict__ rcC,
    const float* __restrict__ winR, const float* __restrict__ hvg,
    const float* __restrict__ ing, const float* __restrict__ dg,
    const float* __restrict__ aw, const float* __restrict__ ar,
    const float* __restrict__ zc,
    float* __restrict__ out, float* __restrict__ ws) {
  int c = blockIdx.x >> 3;                     // 0..87
  int b = ((blockIdx.x & 7) << 8) + threadIdx.x;
  Prm p = make_prm(rcR, rcC, winR, hvg, ing, dg, aw, ar, zc);
  float Tz, T0, T1, T2, T3, T4;
  if (c == 0) {
    // ---- chunk 0: 48 steps with gt override, 3 groups of 16 prefetched ----
    float2 iv = ((const float2*)(ws + INIT_OFF))[b];
    Tz = iv.x; T0 = T1 = T2 = T3 = T4 = iv.y;
    const float2* pk2 = ((const float2*)(ws + PACK2_OFF)) + b;
    const float*  pu  = ws + PACKU_OFF + b;
    const float*  pg  = ws + PACKG_OFF + b;
    float* op = out + (size_t)b * TLEN;
    for (int g = 0; g < 3; ++g) {
      float2 f2[16]; float uv[16], gt[16];
      #pragma unroll
      for (int k = 0; k < 16; ++k) {
        size_t o = (size_t)(g * 16 + k) * BATCH;
        f2[k] = pk2[o]; uv[k] = pu[o]; gt[k] = pg[o];
      }
      float o0 = 0.f, o1 = 0.f, o2 = 0.f;
      #pragma unroll
      for (int k = 0; k < 16; ++k) {
        float d = fmaf(p.K[0], T0, uv[k]);
        d = fmaf(p.K[1], T1, d); d = fmaf(p.K[2], T2, d);
        d = fmaf(p.K[3], T3, d); d = fmaf(p.K[4], T4, d);
        float tzn = fmaf(p.AZ, Tz, d);
        #pragma unroll
        for (int j = 0; j < 5; ++j) {
          float* T = (j == 0) ? &T0 : (j == 1) ? &T1 : (j == 2) ? &T2 : (j == 3) ? &T3 : &T4;
          *T = fmaf(p.M[j], *T, fmaf(p.P[j], Tz, fmaf(p.P[j], f2[k].x, p.Q[j] * f2[k].y)));
        }
        int ph = k & 3;
        if (ph == 0) o0 = tzn; else if (ph == 1) o1 = tzn;
        else if (ph == 2) o2 = tzn;
        else *(float4*)(op + g * 16 + (k - 3)) = make_float4(o0, o1, o2, tzn);
        Tz = (g * 16 + k < 47) ? gt[k] : tzn;
      }
    }
  } else {
    // ---- chunks 1..87: 16 steps from zero state, fully prefetched ----
    int t0 = CL0 + (c - 1) * CL2;
    const float2* pk2 = ((const float2*)(ws + PACK2_OFF)) + (size_t)t0 * BATCH + b;
    const float*  pu  = ws + PACKU_OFF + (size_t)t0 * BATCH + b;
    float2 f2[16]; float uv[16];
    #pragma unroll
    for (int k = 0; k < 16; ++k) {
      f2[k] = pk2[(size_t)k * BATCH];
      uv[k] = pu[(size_t)k * BATCH];
    }
    Tz = 0.f; T0 = T1 = T2 = T3 = T4 = 0.f;
    float* op = out + (size_t)b * TLEN + t0;
    float o0 = 0.f, o1 = 0.f, o2 = 0.f;
    #pragma unroll
    for (int k = 0; k < 16; ++k) {
      float d = fmaf(p.K[0], T0, uv[k]);
      d = fmaf(p.K[1], T1, d); d = fmaf(p.K[2], T2, d);
      d = fmaf(p.K[3], T3, d); d = fmaf(p.K[4], T4, d);
      float tzn = fmaf(p.AZ, Tz, d);
      T0 = fmaf(p.M[0], T0, fmaf(p.P[0], Tz, fmaf(p.P[0], f2[k].x, p.Q[0] * f2[k].y)));
      T1 = fmaf(p.M[1], T1, fmaf(p.P[1], Tz, fmaf(p.P[1], f2[k].x, p.Q[1] * f2[k].y)));
      T2 = fmaf(p.M[2], T2, fmaf(p.P[2], Tz, fmaf(p.P[2], f2[k].x, p.Q[2] * f2[k].y)));
      T3 = fmaf(p.M[3], T3, fmaf(p.P[3], Tz, fmaf(p.P[3], f2[k].x, p.Q[3] * f2[k].y)));
      T4 = fmaf(p.M[4], T4, fmaf(p.P[4], Tz, fmaf(p.P[4], f2[k].x, p.Q[4] * f2[k].y)));
      int ph = k & 3;
      if (ph == 0) o0 = tzn; else if (ph == 1) o1 = tzn;
      else if (ph == 2) o2 = tzn;
      else *(float4*)(op + (k - 3)) = make_float4(o0, o1, o2, tzn);
      Tz = tzn;
    }
  }
  float* e = ws + E_OFF + ((size_t)c * BATCH + b) * 8;
  *(float4*)e       = make_float4(Tz, T0, T1, T2);
  *(float4*)(e + 4) = make_float4(T3, T4, 0.f, 0.f);
}

// ============ K2b: sequential chunk-state combine, A^16 in registers ============
__global__ __launch_bounds__(64) void k2b_combine(
    const float* __restrict__ rcR, const float* __restrict__ rcC,
    const float* __restrict__ winR, const float* __restrict__ hvg,
    const float* __restrict__ ing, const float* __restrict__ dg,
    const float* __restrict__ aw, const float* __restrict__ ar,
    const float* __restrict__ zc, float* __restrict__ ws) {
  int b = blockIdx.x * 64 + threadIdx.x;  // < BATCH (32 blocks x 64)
  Prm p = make_prm(rcR, rcC, winR, hvg, ing, dg, aw, ar, zc);
  // Build A (sparse) then square 4x -> A^16, all in registers.
  float A[36];
  #pragma unroll
  for (int i = 0; i < 36; ++i) A[i] = 0.f;
  A[0] = p.AZ;
  #pragma unroll
  for (int j = 0; j < 5; ++j) {
    A[1 + j]             = p.K[j];
    A[(1 + j) * 6]       = p.P[j];
    A[(1 + j) * 6 + 1 + j] = p.M[j];
  }
  #pragma unroll
  for (int it = 0; it < 4; ++it) {
    float Bm[36];
    #pragma unroll
    for (int i = 0; i < 6; ++i)
      #pragma unroll
      for (int j = 0; j < 6; ++j) {
        float s = 0.f;
        #pragma unroll
        for (int m = 0; m < 6; ++m) s = fmaf(A[i * 6 + m], A[m * 6 + j], s);
        Bm[i * 6 + j] = s;
      }
    #pragma unroll
    for (int i = 0; i < 36; ++i) A[i] = Bm[i];
  }
  const float* e = ws + E_OFF;
  float4 h0 = *(const float4*)(e + (size_t)b * 8);
  float2 h1 = *(const float2*)(e + (size_t)b * 8 + 4);
  float Xs[6] = {h0.x, h0.y, h0.z, h0.w, h1.x, h1.y};   // X_1 = exact end of chunk 0
  for (int base = 1; base <= 87; base += 8) {
    float4 q0[8]; float2 q1[8];
    #pragma unroll
    for (int i = 0; i < 8; ++i) {              // 8 independent loads in flight
      int cI = base + i;
      if (cI <= 86) {
        const float* en = e + ((size_t)cI * BATCH + b) * 8;
        q0[i] = *(const float4*)en;
        q1[i] = *(const float2*)(en + 4);
      }
    }
    #pragma unroll
    for (int i = 0; i < 8; ++i) {
      int cI = base + i;
      if (cI > 87) break;
      float* xc = ws + XC_OFF + ((size_t)cI * BATCH + b) * 8;   // [c][b] coalesced
      *(float4*)xc       = make_float4(Xs[0], Xs[1], Xs[2], Xs[3]);
      *(float2*)(xc + 4) = make_float2(Xs[4], Xs[5]);
      if (cI <= 86) {
        float ecur[6] = {q0[i].x, q0[i].y, q0[i].z, q0[i].w, q1[i].x, q1[i].y};
        float Y[6];
        #pragma unroll
        for (int r = 0; r < 6; ++r) {
          float s = ecur[r];
          #pragma unroll
          for (int m = 0; m < 6; ++m) s = fmaf(A[r * 6 + m], Xs[m], s);
          Y[r] = s;
        }
        #pragma unroll
        for (int j = 0; j < 6; ++j) Xs[j] = Y[j];
      }
    }
  }
}

// ============ K2c: superposition correction for t >= 48, V in registers ============
__global__ __launch_bounds__(256) void k2c_correct(
    const float* __restrict__ rcR, const float* __restrict__ rcC,
    const float* __restrict__ winR, const float* __restrict__ hvg,
    const float* __restrict__ ing, const float* __restrict__ dg,
    const float* __restrict__ aw, const float* __restrict__ ar,
    const float* __restrict__ zc,
    float* __restrict__ out, const float* __restrict__ ws) {
  int tid = blockIdx.x * 256 + threadIdx.x;  // < BATCH*TREST (exact grid)
  int b  = tid / TREST;
  int tt = tid - b * TREST;          // 0..1391
  int c  = (tt >> 4) + 1;            // 1..87
  int kk = tt & 15;
  Prm p = make_prm(rcR, rcC, winR, hvg, ing, dg, aw, ar, zc);
  // V[kk] = row0(A^(kk+1)) via sparse v <- v*A recurrence
  float v0 = p.AZ, v1 = p.K[0], v2 = p.K[1], v3 = p.K[2], v4 = p.K[3], v5 = p.K[4];
  for (int i = 0; i < kk; ++i) {
    float n0 = v0 * p.AZ;
    n0 = fmaf(v1, p.P[0], n0); n0 = fmaf(v2, p.P[1], n0); n0 = fmaf(v3, p.P[2], n0);
    n0 = fmaf(v4, p.P[3], n0); n0 = fmaf(v5, p.P[4], n0);
    float n1 = fmaf(v0, p.K[0], v1 * p.M[0]);
    float n2 = fmaf(v0, p.K[1], v2 * p.M[1]);
    float n3 = fmaf(v0, p.K[2], v3 * p.M[2]);
    float n4 = fmaf(v0, p.K[3], v4 * p.M[3]);
    float n5 = fmaf(v0, p.K[4], v5 * p.M[4]);
    v0 = n0; v1 = n1; v2 = n2; v3 = n3; v4 = n4; v5 = n5;
  }
  const float* xc = ws + XC_OFF + ((size_t)c * BATCH + b) * 8;
  float4 x0 = *(const float4*)xc;
  float2 x1 = *(const float2*)(xc + 4);
  size_t o = (size_t)b * TLEN + CL0 + tt;
  float s = out[o];
  s = fmaf(v0, x0.x, s); s = fmaf(v1, x0.y, s); s = fmaf(v2, x0.z, s);
  s = fmaf(v3, x0.w, s); s = fmaf(v4, x1.x, s); s = fmaf(v5, x1.y, s);
  out[o] = s;
}

// ============ Fallback: plain per-batch scan (if ws too small) ============
__global__ void k_fallback(const float* __restrict__ X,
    const float* __restrict__ rcR, const float* __restrict__ rcC,
    const float* __restrict__ winR, const float* __restrict__ hvg,
    const float* __restrict__ W1, const float* __restrict__ B1,
    const float* __restrict__ W2, const float* __restrict__ B2,
    const float* __restrict__ ing, const float* __restrict__ dg,
    const float* __restrict__ aw, const float* __restrict__ ar,
    const float* __restrict__ zc, float* __restrict__ out) {
  int b = blockIdx.x * 64 + threadIdx.x;
  if (b >= BATCH) return;
  Prm p = make_prm(rcR, rcC, winR, hvg, ing, dg, aw, ar, zc);
  const float* xb = X + (size_t)b * T7;
  float Tz = xb[0];
  float tm = fmaf(0.7f, xb[0], 0.3f * xb[1]);
  float Tm[5] = {tm, tm, tm, tm, tm};
  for (int t = 0; t < TLEN; ++t) {
    const float* x = xb + t * 7;
    float ta = x[1], so = x[2], x3 = x[3], x4 = x[4], x5 = x[5], hv = x[6];
    float acc = B2[0];
    #pragma unroll
    for (int h = 0; h < 32; ++h) {
      float z = fmaf(W1[2 * h], x3, fmaf(W1[2 * h + 1], x4, B1[h]));
      acc = fmaf(W2[h], fmaxf(z, 0.f), acc);
    }
    float sch = __frcp_rn(1.f + __expf(-acc)) + x5;
    float q = fmaf(p.cInt, sch, fmaf(p.cHv, hv, p.cDir * so));
    float u = fmaf(p.dtczw, ta, p.dtcz * q);
    float d = u;
    #pragma unroll
    for (int j = 0; j < 5; ++j) d = fmaf(p.K[j], Tm[j], d);
    float tzn = fmaf(p.AZ, Tz, d);
    #pragma unroll
    for (int j = 0; j < 5; ++j)
      Tm[j] = fmaf(p.M[j], Tm[j], fmaf(p.P[j], Tz, fmaf(p.P[j], ta, p.Q[j] * so)));
    out[(size_t)b * TLEN + t] = tzn;
    Tz = (t < 47) ? x[7] : tzn;
  }
}

extern "C" void kernel_launch(void* const* d_in, const int* in_sizes, int n_in,
                              void* d_out, int out_size, void* d_ws, size_t ws_size,
                              hipStream_t stream) {
  const float* X    = (const float*)d_in[0];
  const float* rcR  = (const float*)d_in[1];
  const float* rcC  = (const float*)d_in[2];
  const float* winR = (const float*)d_in[3];
  const float* hvg  = (const float*)d_in[4];
  const float* W1   = (const float*)d_in[5];
  const float* B1   = (const float*)d_in[6];
  const float* W2   = (const float*)d_in[7];
  const float* B2   = (const float*)d_in[8];
  const float* ing  = (const float*)d_in[9];
  const float* dg   = (const float*)d_in[10];
  const float* aw   = (const float*)d_in[11];
  const float* ar   = (const float*)d_in[12];
  const float* zc   = (const float*)d_in[13];
  float* out = (float*)d_out;
  float* ws  = (float*)d_ws;

  if (ws_size >= (size_t)WS_FLOATS * sizeof(float)) {
    k1_pack<<<(TLEN / 4) * 8, 256, 0, stream>>>(X, rcR, rcC, winR, hvg,
                                                W1, B1, W2, B2, ing, dg, aw, ar, zc, ws);
    k2_scan<<<NCH * 8, 256, 0, stream>>>(rcR, rcC, winR, hvg, ing, dg, aw, ar, zc,
                                         out, ws);
    k2b_combine<<<32, 64, 0, stream>>>(rcR, rcC, winR, hvg, ing, dg, aw, ar, zc, ws);
    k2c_correct<<<(BATCH * TREST) / 256, 256, 0, stream>>>(rcR, rcC, winR, hvg,
                                                           ing, dg, aw, ar, zc, out, ws);
  } else {
    k_fallback<<<BATCH / 64, 64, 0, stream>>>(X, rcR, rcC, winR, hvg, W1, B1, W2, B2,
                                              ing, dg, aw, ar, zc, out);
  }
}